// Round 5
// baseline (270.668 us; speedup 1.0000x reference)
//
#include <hip/hip_runtime.h>

using short8   = __attribute__((ext_vector_type(8))) short;
using short4v  = __attribute__((ext_vector_type(4))) short;
using f32x4    = __attribute__((ext_vector_type(4))) float;
using ushort4v = __attribute__((ext_vector_type(4))) unsigned short;

#define BN_EPS 1e-5f
// log2(e)/sqrt(32): folded into q projection so softmax uses native exp2
#define ATT_SCALE_LOG2E 0.2550348347988049f

__device__ __forceinline__ unsigned short f2bf(float f) {
    union { float f; unsigned u; } v; v.f = f;
    return (unsigned short)((v.u + 0x7FFFu + ((v.u >> 16) & 1u)) >> 16);  // RNE
}

// pack two f32 -> two bf16 (round-half-up): a in low 16, b in high 16
__device__ __forceinline__ unsigned pack2bf(float a, float b) {
    union { float f; unsigned u; } ua, ub; ua.f = a; ub.f = b;
    return __builtin_amdgcn_perm(ub.u + 0x8000u, ua.u + 0x8000u, 0x07060302u);
}

// ---------------------------------------------------------------------------
// Kernel 0: weights -> bf16; fold conv-bias + BN into per-row (scale, offset).
// Rows: 0-31 q, 32-63 k, 64-319 v.
// ---------------------------------------------------------------------------
__global__ void prep_kernel(
    const float* __restrict__ qw, const float* __restrict__ qb,
    const float* __restrict__ qg, const float* __restrict__ qbe,
    const float* __restrict__ qm, const float* __restrict__ qv,
    const float* __restrict__ kw, const float* __restrict__ kb,
    const float* __restrict__ kg, const float* __restrict__ kbe,
    const float* __restrict__ km, const float* __restrict__ kvv,
    const float* __restrict__ vw, const float* __restrict__ vb,
    const float* __restrict__ vg, const float* __restrict__ vbe,
    const float* __restrict__ vm, const float* __restrict__ vv,
    unsigned short* __restrict__ wq, float* __restrict__ scale,
    float* __restrict__ off)
{
    int r = blockIdx.x;      // 0..319
    int t = threadIdx.x;     // 0..63
    const float *wsrc, *g, *be, *mn, *vr, *bi;
    int rl;
    if (r < 32)      { rl = r;      wsrc = qw; g = qg; be = qbe; mn = qm; vr = qv;  bi = qb; }
    else if (r < 64) { rl = r - 32; wsrc = kw; g = kg; be = kbe; mn = km; vr = kvv; bi = kb; }
    else             { rl = r - 64; wsrc = vw; g = vg; be = vbe; mn = vm; vr = vv;  bi = vb; }

    float4 w4 = *(const float4*)(wsrc + rl * 256 + t * 4);
    ushort4v o;
    o.x = f2bf(w4.x); o.y = f2bf(w4.y); o.z = f2bf(w4.z); o.w = f2bf(w4.w);
    *(ushort4v*)(wq + r * 256 + t * 4) = o;

    if (t == 0) {
        float inv = g[rl] * rsqrtf(vr[rl] + BN_EPS);
        float ofv = bi[rl] * inv + be[rl] - mn[rl] * inv;
        float s = (r < 32) ? ATT_SCALE_LOG2E : 1.0f;
        scale[r] = inv * s;
        off[r]   = ofv * s;
    }
}

// ---------------------------------------------------------------------------
// Kernel 1: projections (r2 version — best measured). bx>>8 = g:
// 0: q(x1), 1: k(x2), 2: v ALL 256 rows (x2). Grid 768.
// q_t/k_t: [b][n][32] bf16.  v_ws: TILE-BLOCKED [b*64+nt][256][64] bf16.
// ---------------------------------------------------------------------------
#define XT_PITCH 264

__global__ __launch_bounds__(256, 4) void proj_kernel(
    const float* __restrict__ x1, const float* __restrict__ x2,
    const unsigned short* __restrict__ wq,
    const float* __restrict__ scale, const float* __restrict__ off,
    unsigned short* __restrict__ q_t, unsigned short* __restrict__ k_t,
    unsigned short* __restrict__ v_ws)
{
    __shared__ __align__(16) unsigned short Xt[64 * XT_PITCH];   // 33792 B
    int bx = blockIdx.x;
    int g  = bx >> 8;        // 0,1,2
    int t2 = bx & 255;
    int nt = t2 & 63;
    int b  = t2 >> 6;
    int n0 = nt * 64;
    int tid = threadIdx.x;
    int wv = tid >> 6, lane = tid & 63;
    int m16 = lane & 15, qd = lane >> 4;

    const float* xb = ((g == 0) ? x1 : x2) + (size_t)b * 256 * 4096 + n0 + lane;

    // octet-gather transpose: n = lane, channels 8*o..8*o+7, o = wv*8+i
    #pragma unroll 2
    for (int i = 0; i < 8; ++i) {
        int o = wv * 8 + i;                       // 0..31
        const float* src = xb + (size_t)(o * 8) * 4096;
        uint4 dw;
        dw.x = pack2bf(src[0],                src[(size_t)1 * 4096]);
        dw.y = pack2bf(src[(size_t)2 * 4096], src[(size_t)3 * 4096]);
        dw.z = pack2bf(src[(size_t)4 * 4096], src[(size_t)5 * 4096]);
        dw.w = pack2bf(src[(size_t)6 * 4096], src[(size_t)7 * 4096]);
        *(uint4*)&Xt[lane * XT_PITCH + o * 8] = dw;
    }
    __syncthreads();

    f32x4 zero4 = {0.f, 0.f, 0.f, 0.f};

    if (g < 2) {
        int rb = g * 32;
        f32x4 acc0 = zero4, acc1 = zero4;
        #pragma unroll 2
        for (int s = 0; s < 8; ++s) {
            short8 w0 = *(const short8*)(wq + (size_t)(rb +      m16) * 256 + s * 32 + qd * 8);
            short8 w1 = *(const short8*)(wq + (size_t)(rb + 16 + m16) * 256 + s * 32 + qd * 8);
            short8 xf = *(const short8*)&Xt[(16 * wv + m16) * XT_PITCH + s * 32 + qd * 8];
            acc0 = __builtin_amdgcn_mfma_f32_16x16x32_bf16(w0, xf, acc0, 0, 0, 0);
            acc1 = __builtin_amdgcn_mfma_f32_16x16x32_bf16(w1, xf, acc1, 0, 0, 0);
        }
        unsigned short* dst = (g == 0) ? q_t : k_t;
        int ncol = n0 + 16 * wv + m16;
        #pragma unroll
        for (int tm = 0; tm < 2; ++tm) {
            f32x4 acc = tm ? acc1 : acc0;
            int r0 = 16 * tm + 4 * qd;
            float4 sc = *(const float4*)(scale + rb + r0);
            float4 of = *(const float4*)(off   + rb + r0);
            ushort4v o;
            o.x = f2bf(acc.x * sc.x + of.x);
            o.y = f2bf(acc.y * sc.y + of.y);
            o.z = f2bf(acc.z * sc.z + of.z);
            o.w = f2bf(acc.w * sc.w + of.w);
            *(ushort4v*)(dst + ((size_t)b * 4096 + ncol) * 32 + r0) = o;
        }
    } else {
        // v: all 256 rows from one x2 transpose
        f32x4 acc[4][4];
        #pragma unroll
        for (int rr = 0; rr < 4; ++rr)
            #pragma unroll
            for (int tm = 0; tm < 4; ++tm) acc[rr][tm] = zero4;
        #pragma unroll 1
        for (int s = 0; s < 8; ++s) {
            short8 xf[4];
            #pragma unroll
            for (int tm = 0; tm < 4; ++tm)
                xf[tm] = *(const short8*)&Xt[(16 * tm + m16) * XT_PITCH + s * 32 + qd * 8];
            #pragma unroll
            for (int rr = 0; rr < 4; ++rr) {
                short8 wf = *(const short8*)(wq + (size_t)(64 + rr * 64 + 16 * wv + m16) * 256 + s * 32 + qd * 8);
                #pragma unroll
                for (int tm = 0; tm < 4; ++tm)
                    acc[rr][tm] = __builtin_amdgcn_mfma_f32_16x16x32_bf16(xf[tm], wf, acc[rr][tm], 0, 0, 0);
            }
        }
        unsigned short* vt = v_ws + (size_t)(b * 64 + nt) * 256 * 64;
        #pragma unroll
        for (int rr = 0; rr < 4; ++rr) {
            int c = rr * 64 + 16 * wv + m16;
            float sc = scale[64 + c], of = off[64 + c];
            #pragma unroll
            for (int tm = 0; tm < 4; ++tm) {
                int nloc = 16 * tm + 4 * qd;
                ushort4v o;
                o.x = f2bf(acc[rr][tm].x * sc + of);
                o.y = f2bf(acc[rr][tm].y * sc + of);
                o.z = f2bf(acc[rr][tm].z * sc + of);
                o.w = f2bf(acc[rr][tm].w * sc + of);
                *(ushort4v*)(vt + c * 64 + nloc) = o;
            }
        }
    }
}

// ---------------------------------------------------------------------------
// Kernel 2: flash attention v5 — K-LOCAL PV, ZERO LDS / ZERO BARRIERS in the
// main loop. Block = 8 waves (512 thr) = (kh 0..3, ch 0..1), 64q x 128c,
// grid 512 (4b x 64qg x 2cg, XCD-pinned via low bits). Wave (kh,ch) owns
// key-slice kh (16 keys per 64-key tile) and channel-half ch (64c).
// Two key-tiles are FUSED per PV MFMA: contraction slot s of mfma_16x16x32
// maps to (tile parity (s&4)>>2, key 4*(s>>3)+(s&3)), so the A-fragment is
// the wave's OWN exp2'd S values from tiles (t, t+1) — entirely in-lane
// (P never leaves registers). B-fragment = two 8B V loads glued together.
// QK is 2x redundant across ch (in-register, negligible). Per-wave partial
// O accumulators (over its 16-key slices) are combined once at the end via
// a 2-round LDS tree. Waves run all 4096 keys fully independently.
// ---------------------------------------------------------------------------
__global__ __launch_bounds__(512, 2) void flash_kernel(
    const unsigned short* __restrict__ q_t, const unsigned short* __restrict__ k_t,
    const unsigned short* __restrict__ v_ws, float* __restrict__ out)
{
    __shared__ __align__(16) float Excg[4 * 4096];   // 64 KB: 4 regions x 16 KB
    __shared__ __align__(16) float Lsh[256];         // 1 KB

    int bx = blockIdx.x;                   // 512 blocks
    int cg = (bx >> 2) & 1;
    int b  = bx & 3;
    int qg = bx >> 3;                      // 0..63
    int q0 = qg * 64;
    int cb = cg * 128;

    int tid = threadIdx.x;
    int wv  = tid >> 6, lane = tid & 63;
    int m16 = lane & 15, qd = lane >> 4;
    int kh  = wv >> 1;                     // 0..3: 16-key slice within tile
    int ch  = wv & 1;                      // 0..1: 64-channel half

    // ---- global fragment bases (per-lane) ----
    // K: [b][k][32]; tile t at +t*2048 shorts
    const unsigned short* kbase = k_t + ((size_t)b * 4096 + kh * 16 + m16) * 32 + qd * 8;
    // V: tile-blocked [b*64+t][256][64]; tile stride 16384 shorts
    const unsigned short* vbase = v_ws + (size_t)b * 1048576
                                + (size_t)(cb + ch * 64 + m16) * 64 + kh * 16 + qd * 4;

    // ---- persistent Q fragments (all 4 q-tiles) ----
    const unsigned short* qb = q_t + ((size_t)b * 4096 + q0) * 32;
    short8 Qf[4];
    #pragma unroll
    for (int qt = 0; qt < 4; ++qt)
        Qf[qt] = *(const short8*)(qb + (size_t)(qt * 16 + m16) * 32 + qd * 8);

    f32x4 zero4 = {0.f, 0.f, 0.f, 0.f};
    f32x4 acc[4][4];
    #pragma unroll
    for (int qt = 0; qt < 4; ++qt)
        #pragma unroll
        for (int ct = 0; ct < 4; ++ct) acc[qt][ct] = zero4;
    float lsum[4] = {0.f, 0.f, 0.f, 0.f};

    // ---- double-buffered fragments: K (2 tiles) + V (4 ct x 2 tiles) ----
    short8  K0A, K1A, K0B, K1B;
    short4v VA[4][2], VB[4][2];
    K0A = *(const short8*)kbase;
    K1A = *(const short8*)(kbase + 2048);
    #pragma unroll
    for (int ct = 0; ct < 4; ++ct) {
        VA[ct][0] = *(const short4v*)(vbase + ct * 1024);
        VA[ct][1] = *(const short4v*)(vbase + 16384 + ct * 1024);
    }

    // one superepoch: consume 2 tiles (K0c/K1c, Vc); prefetch tiles (2*nse, +1)
    auto step = [&](const short8& K0c, const short8& K1c, short4v (&Vc)[4][2],
                    short8& K0n, short8& K1n, short4v (&Vn)[4][2], int nse) {
        int kt = nse * 2;
        K0n = *(const short8*)(kbase + (size_t)kt * 2048);
        K1n = *(const short8*)(kbase + (size_t)(kt + 1) * 2048);
        #pragma unroll
        for (int ct = 0; ct < 4; ++ct) {
            Vn[ct][0] = *(const short4v*)(vbase + (size_t)kt * 16384 + ct * 1024);
            Vn[ct][1] = *(const short4v*)(vbase + (size_t)(kt + 1) * 16384 + ct * 1024);
        }

        // ---- QK both tiles: S^T (16k x 16q) per qt; k-local = 4qd+r ----
        f32x4 SA[4], SB[4];
        #pragma unroll
        for (int qt = 0; qt < 4; ++qt) {
            SA[qt] = __builtin_amdgcn_mfma_f32_16x16x32_bf16(K0c, Qf[qt], zero4, 0, 0, 0);
            SB[qt] = __builtin_amdgcn_mfma_f32_16x16x32_bf16(K1c, Qf[qt], zero4, 0, 0, 0);
        }

        // ---- exp2 + pack (in-lane A-frags) + PV ----
        #pragma unroll
        for (int qt = 0; qt < 4; ++qt) {
            float a0 = __builtin_amdgcn_exp2f(SA[qt].x), a1 = __builtin_amdgcn_exp2f(SA[qt].y);
            float a2 = __builtin_amdgcn_exp2f(SA[qt].z), a3 = __builtin_amdgcn_exp2f(SA[qt].w);
            float b0 = __builtin_amdgcn_exp2f(SB[qt].x), b1 = __builtin_amdgcn_exp2f(SB[qt].y);
            float b2 = __builtin_amdgcn_exp2f(SB[qt].z), b3 = __builtin_amdgcn_exp2f(SB[qt].w);
            lsum[qt] += ((a0 + a1) + (a2 + a3)) + ((b0 + b1) + (b2 + b3));
            union { uint4 u; short8 s; } ap;
            ap.u.x = pack2bf(a0, a1); ap.u.y = pack2bf(a2, a3);
            ap.u.z = pack2bf(b0, b1); ap.u.w = pack2bf(b2, b3);
            #pragma unroll
            for (int ct = 0; ct < 4; ++ct) {
                short8 Vf = __builtin_shufflevector(Vc[ct][0], Vc[ct][1],
                                                    0, 1, 2, 3, 4, 5, 6, 7);
                acc[qt][ct] = __builtin_amdgcn_mfma_f32_16x16x32_bf16(ap.s, Vf, acc[qt][ct], 0, 0, 0);
            }
        }
    };

    // 32 superepochs (64 tiles); prefetch clamped at the tail
    #pragma unroll 1
    for (int se = 0; se < 32; se += 2) {
        step(K0A, K1A, VA, K0B, K1B, VB, se + 1);
        step(K0B, K1B, VB, K0A, K1A, VA, (se + 2 > 31) ? 31 : se + 2);
    }

    // ---- softmax denominators: qd-reduce in-wave; ch=0 waves publish ----
    #pragma unroll
    for (int qt = 0; qt < 4; ++qt) {
        float l = lsum[qt];
        l += __shfl_xor(l, 16);
        l += __shfl_xor(l, 32);
        if (ch == 0 && lane < 16) Lsh[kh * 64 + qt * 16 + lane] = l;
    }

    // ---- O-combine over kh: 2-round LDS tree (regions of 16 KB) ----
    // round 1: kh=2,3 write; kh=0,1 add partner (kh+2, same ch)
    if (kh >= 2) {
        f32x4* dst = (f32x4*)(Excg + (wv - 4) * 4096) + lane * 16;
        #pragma unroll
        for (int qt = 0; qt < 4; ++qt)
            #pragma unroll
            for (int ct = 0; ct < 4; ++ct) dst[qt * 4 + ct] = acc[qt][ct];
    }
    __syncthreads();
    if (kh < 2) {
        const f32x4* src = (const f32x4*)(Excg + wv * 4096) + lane * 16;
        #pragma unroll
        for (int qt = 0; qt < 4; ++qt)
            #pragma unroll
            for (int ct = 0; ct < 4; ++ct) acc[qt][ct] += src[qt * 4 + ct];
    }
    __syncthreads();
    // round 2: kh=1 writes; kh=0 adds partner (kh+1... wv+2, same ch)
    if (kh == 1) {
        f32x4* dst = (f32x4*)(Excg + (wv - 2) * 4096) + lane * 16;
        #pragma unroll
        for (int qt = 0; qt < 4; ++qt)
            #pragma unroll
            for (int ct = 0; ct < 4; ++ct) dst[qt * 4 + ct] = acc[qt][ct];
    }
    __syncthreads();
    if (kh == 0) {
        const f32x4* src = (const f32x4*)(Excg + wv * 4096) + lane * 16;
        #pragma unroll
        for (int qt = 0; qt < 4; ++qt)
            #pragma unroll
            for (int ct = 0; ct < 4; ++ct) acc[qt][ct] += src[qt * 4 + ct];

        // ---- scale by 1/denominator and store ----
        #pragma unroll
        for (int qt = 0; qt < 4; ++qt) {
            f32x4 s4 = *(const f32x4*)&Lsh[qt * 16 + qd * 4];
            s4 += *(const f32x4*)&Lsh[64  + qt * 16 + qd * 4];
            s4 += *(const f32x4*)&Lsh[128 + qt * 16 + qd * 4];
            s4 += *(const f32x4*)&Lsh[192 + qt * 16 + qd * 4];
            f32x4 inv4;
            inv4.x = __builtin_amdgcn_rcpf(s4.x);
            inv4.y = __builtin_amdgcn_rcpf(s4.y);
            inv4.z = __builtin_amdgcn_rcpf(s4.z);
            inv4.w = __builtin_amdgcn_rcpf(s4.w);
            #pragma unroll
            for (int ct = 0; ct < 4; ++ct) {
                // acc: col=m16=c-local, row=4*qd+r=q-local
                float* ob = out + ((size_t)(b * 256 + cb + ch * 64 + ct * 16 + m16)) * 4096
                                + q0 + qt * 16 + qd * 4;
                float4 o;
                o.x = acc[qt][ct].x * inv4.x;
                o.y = acc[qt][ct].y * inv4.y;
                o.z = acc[qt][ct].z * inv4.z;
                o.w = acc[qt][ct].w * inv4.w;
                *(float4*)ob = o;
            }
        }
    }
}

// ---------------------------------------------------------------------------
// Workspace: wq 320x256 bf16 | scale/off 320 f32 | q_t,k_t [b][n][32] bf16 |
// v_ws tile-blocked [b*64+kt][256][64] bf16. Total ~10.7 MB.
// ---------------------------------------------------------------------------
extern "C" void kernel_launch(void* const* d_in, const int* in_sizes, int n_in,
                              void* d_out, int out_size, void* d_ws, size_t ws_size,
                              hipStream_t stream)
{
    const float* x1  = (const float*)d_in[0];
    const float* x2  = (const float*)d_in[1];
    const float* qw  = (const float*)d_in[2];
    const float* qb  = (const float*)d_in[3];
    const float* qg  = (const float*)d_in[4];
    const float* qbe = (const float*)d_in[5];
    const float* qm  = (const float*)d_in[6];
    const float* qv  = (const float*)d_in[7];
    const float* kw  = (const float*)d_in[8];
    const float* kb  = (const float*)d_in[9];
    const float* kg  = (const float*)d_in[10];
    const float* kbe = (const float*)d_in[11];
    const float* km  = (const float*)d_in[12];
    const float* kvv = (const float*)d_in[13];
    const float* vw  = (const float*)d_in[14];
    const float* vb  = (const float*)d_in[15];
    const float* vg  = (const float*)d_in[16];
    const float* vbe = (const float*)d_in[17];
    const float* vm  = (const float*)d_in[18];
    const float* vv  = (const float*)d_in[19];

    char* ws = (char*)d_ws;
    unsigned short* wq   = (unsigned short*)(ws + 0);
    float*          scale= (float*)(ws + 163840);
    float*          off  = (float*)(ws + 165120);
    unsigned short* q_t  = (unsigned short*)(ws + 166400);
    unsigned short* k_t  = (unsigned short*)(ws + 166400 + 1048576);
    unsigned short* v_ws = (unsigned short*)(ws + 166400 + 2097152);

    prep_kernel<<<320, 64, 0, stream>>>(qw, qb, qg, qbe, qm, qv,
                                        kw, kb, kg, kbe, km, kvv,
                                        vw, vb, vg, vbe, vm, vv,
                                        wq, scale, off);
    proj_kernel<<<768, 256, 0, stream>>>(x1, x2, wq, scale, off, q_t, k_t, v_ws);
    flash_kernel<<<512, 512, 0, stream>>>(q_t, k_t, v_ws, (float*)d_out);
}

// Round 6
// 218.991 us; speedup vs baseline: 1.2360x; 1.2360x over previous
//
#include <hip/hip_runtime.h>

using short8   = __attribute__((ext_vector_type(8))) short;
using f32x4    = __attribute__((ext_vector_type(4))) float;
using ushort4v = __attribute__((ext_vector_type(4))) unsigned short;

#define BN_EPS 1e-5f
// log2(e)/sqrt(32): folded into q projection so softmax uses native exp2
#define ATT_SCALE_LOG2E 0.2550348347988049f

__device__ __forceinline__ unsigned short f2bf(float f) {
    union { float f; unsigned u; } v; v.f = f;
    return (unsigned short)((v.u + 0x7FFFu + ((v.u >> 16) & 1u)) >> 16);  // RNE
}

// pack two f32 -> two bf16 (round-half-up): a in low 16, b in high 16
__device__ __forceinline__ unsigned pack2bf(float a, float b) {
    union { float f; unsigned u; } ua, ub; ua.f = a; ub.f = b;
    return __builtin_amdgcn_perm(ub.u + 0x8000u, ua.u + 0x8000u, 0x07060302u);
}

// async global->LDS, 16B per lane. gp: per-lane global src. lp: wave-uniform
// LDS base (HW adds lane*16).
__device__ __forceinline__ void glds16(const void* gp, void* lp) {
    __builtin_amdgcn_global_load_lds(
        (const __attribute__((address_space(1))) unsigned*)gp,
        (__attribute__((address_space(3))) unsigned*)lp, 16, 0, 0);
}

// ---------------------------------------------------------------------------
// Kernel 0: weights -> bf16; fold conv-bias + BN into per-row (scale, offset).
// Rows: 0-31 q, 32-63 k, 64-319 v.
// ---------------------------------------------------------------------------
__global__ void prep_kernel(
    const float* __restrict__ qw, const float* __restrict__ qb,
    const float* __restrict__ qg, const float* __restrict__ qbe,
    const float* __restrict__ qm, const float* __restrict__ qv,
    const float* __restrict__ kw, const float* __restrict__ kb,
    const float* __restrict__ kg, const float* __restrict__ kbe,
    const float* __restrict__ km, const float* __restrict__ kvv,
    const float* __restrict__ vw, const float* __restrict__ vb,
    const float* __restrict__ vg, const float* __restrict__ vbe,
    const float* __restrict__ vm, const float* __restrict__ vv,
    unsigned short* __restrict__ wq, float* __restrict__ scale,
    float* __restrict__ off)
{
    int r = blockIdx.x;      // 0..319
    int t = threadIdx.x;     // 0..63
    const float *wsrc, *g, *be, *mn, *vr, *bi;
    int rl;
    if (r < 32)      { rl = r;      wsrc = qw; g = qg; be = qbe; mn = qm; vr = qv;  bi = qb; }
    else if (r < 64) { rl = r - 32; wsrc = kw; g = kg; be = kbe; mn = km; vr = kvv; bi = kb; }
    else             { rl = r - 64; wsrc = vw; g = vg; be = vbe; mn = vm; vr = vv;  bi = vb; }

    float4 w4 = *(const float4*)(wsrc + rl * 256 + t * 4);
    ushort4v o;
    o.x = f2bf(w4.x); o.y = f2bf(w4.y); o.z = f2bf(w4.z); o.w = f2bf(w4.w);
    *(ushort4v*)(wq + r * 256 + t * 4) = o;

    if (t == 0) {
        float inv = g[rl] * rsqrtf(vr[rl] + BN_EPS);
        float ofv = bi[rl] * inv + be[rl] - mn[rl] * inv;
        float s = (r < 32) ? ATT_SCALE_LOG2E : 1.0f;
        scale[r] = inv * s;
        off[r]   = ofv * s;
    }
}

// ---------------------------------------------------------------------------
// Kernel 1: projections (r2 version — best measured). bx>>8 = g:
// 0: q(x1), 1: k(x2), 2: v ALL 256 rows (x2). Grid 768.
// q_t/k_t: [b][n][32] bf16.  v_ws: TILE-BLOCKED [b*64+nt][256][64] bf16.
// ---------------------------------------------------------------------------
#define XT_PITCH 264

__global__ __launch_bounds__(256, 4) void proj_kernel(
    const float* __restrict__ x1, const float* __restrict__ x2,
    const unsigned short* __restrict__ wq,
    const float* __restrict__ scale, const float* __restrict__ off,
    unsigned short* __restrict__ q_t, unsigned short* __restrict__ k_t,
    unsigned short* __restrict__ v_ws)
{
    __shared__ __align__(16) unsigned short Xt[64 * XT_PITCH];   // 33792 B
    int bx = blockIdx.x;
    int g  = bx >> 8;        // 0,1,2
    int t2 = bx & 255;
    int nt = t2 & 63;
    int b  = t2 >> 6;
    int n0 = nt * 64;
    int tid = threadIdx.x;
    int wv = tid >> 6, lane = tid & 63;
    int m16 = lane & 15, qd = lane >> 4;

    const float* xb = ((g == 0) ? x1 : x2) + (size_t)b * 256 * 4096 + n0 + lane;

    // octet-gather transpose: n = lane, channels 8*o..8*o+7, o = wv*8+i
    #pragma unroll 2
    for (int i = 0; i < 8; ++i) {
        int o = wv * 8 + i;                       // 0..31
        const float* src = xb + (size_t)(o * 8) * 4096;
        uint4 dw;
        dw.x = pack2bf(src[0],                src[(size_t)1 * 4096]);
        dw.y = pack2bf(src[(size_t)2 * 4096], src[(size_t)3 * 4096]);
        dw.z = pack2bf(src[(size_t)4 * 4096], src[(size_t)5 * 4096]);
        dw.w = pack2bf(src[(size_t)6 * 4096], src[(size_t)7 * 4096]);
        *(uint4*)&Xt[lane * XT_PITCH + o * 8] = dw;
    }
    __syncthreads();

    f32x4 zero4 = {0.f, 0.f, 0.f, 0.f};

    if (g < 2) {
        int rb = g * 32;
        f32x4 acc0 = zero4, acc1 = zero4;
        #pragma unroll 2
        for (int s = 0; s < 8; ++s) {
            short8 w0 = *(const short8*)(wq + (size_t)(rb +      m16) * 256 + s * 32 + qd * 8);
            short8 w1 = *(const short8*)(wq + (size_t)(rb + 16 + m16) * 256 + s * 32 + qd * 8);
            short8 xf = *(const short8*)&Xt[(16 * wv + m16) * XT_PITCH + s * 32 + qd * 8];
            acc0 = __builtin_amdgcn_mfma_f32_16x16x32_bf16(w0, xf, acc0, 0, 0, 0);
            acc1 = __builtin_amdgcn_mfma_f32_16x16x32_bf16(w1, xf, acc1, 0, 0, 0);
        }
        unsigned short* dst = (g == 0) ? q_t : k_t;
        int ncol = n0 + 16 * wv + m16;
        #pragma unroll
        for (int tm = 0; tm < 2; ++tm) {
            f32x4 acc = tm ? acc1 : acc0;
            int r0 = 16 * tm + 4 * qd;
            float4 sc = *(const float4*)(scale + rb + r0);
            float4 of = *(const float4*)(off   + rb + r0);
            ushort4v o;
            o.x = f2bf(acc.x * sc.x + of.x);
            o.y = f2bf(acc.y * sc.y + of.y);
            o.z = f2bf(acc.z * sc.z + of.z);
            o.w = f2bf(acc.w * sc.w + of.w);
            *(ushort4v*)(dst + ((size_t)b * 4096 + ncol) * 32 + r0) = o;
        }
    } else {
        // v: all 256 rows from one x2 transpose
        f32x4 acc[4][4];
        #pragma unroll
        for (int rr = 0; rr < 4; ++rr)
            #pragma unroll
            for (int tm = 0; tm < 4; ++tm) acc[rr][tm] = zero4;
        #pragma unroll 1
        for (int s = 0; s < 8; ++s) {
            short8 xf[4];
            #pragma unroll
            for (int tm = 0; tm < 4; ++tm)
                xf[tm] = *(const short8*)&Xt[(16 * tm + m16) * XT_PITCH + s * 32 + qd * 8];
            #pragma unroll
            for (int rr = 0; rr < 4; ++rr) {
                short8 wf = *(const short8*)(wq + (size_t)(64 + rr * 64 + 16 * wv + m16) * 256 + s * 32 + qd * 8);
                #pragma unroll
                for (int tm = 0; tm < 4; ++tm)
                    acc[rr][tm] = __builtin_amdgcn_mfma_f32_16x16x32_bf16(xf[tm], wf, acc[rr][tm], 0, 0, 0);
            }
        }
        unsigned short* vt = v_ws + (size_t)(b * 64 + nt) * 256 * 64;
        #pragma unroll
        for (int rr = 0; rr < 4; ++rr) {
            int c = rr * 64 + 16 * wv + m16;
            float sc = scale[64 + c], of = off[64 + c];
            #pragma unroll
            for (int tm = 0; tm < 4; ++tm) {
                int nloc = 16 * tm + 4 * qd;
                ushort4v o;
                o.x = f2bf(acc[rr][tm].x * sc + of);
                o.y = f2bf(acc[rr][tm].y * sc + of);
                o.z = f2bf(acc[rr][tm].z * sc + of);
                o.w = f2bf(acc[rr][tm].w * sc + of);
                *(ushort4v*)(vt + c * 64 + nloc) = o;
            }
        }
    }
}

// ---------------------------------------------------------------------------
// Kernel 2: flash attention v6 = v2 EXACTLY, with 32-QUERY BLOCKS for
// occupancy. Block = 4 waves (256 thr), 32 queries x 128 channels, ALL 4096
// keys. Grid 1024 = 128qg x 4b x 2cg, XCD-pinned via low 3 bits. LDS 44.5KB
// -> 3 blocks/CU (v2's grid 512 capped residency at 2; the third block fills
// the barrier-convoy idle that v2/v3/v4 all exposed). Main-loop structure,
// DMA source-swizzles, P swizzle, B1/B2 barriers verbatim from the proven v2:
//   B1: s_waitcnt vmcnt(0) + s_barrier; issue next tile's DMA (K 4KB + V 16KB)
//   QK: wave wv = 16-key slice: 2 MFMAs, 8 exp2/lane -> swizzled 4KB P
//   B2: s_waitcnt lgkmcnt(0) + s_barrier (DMA stays in flight)
//   PV: wave wv = 32-channel slice: 4 Ap + 4 V b128 reads, 8 MFMAs, setprio.
// ---------------------------------------------------------------------------
__global__ __launch_bounds__(256, 3) void flash_kernel(
    const unsigned short* __restrict__ q_t, const unsigned short* __restrict__ k_t,
    const unsigned short* __restrict__ v_ws, float* __restrict__ out)
{
    // Kbuf 2x4KB @0 | Vbuf 2x16KB @8192 | P 4KB @40960 | Lsh 512B @45056
    __shared__ __align__(16) unsigned char Smem[45568];

    int bx = blockIdx.x;                   // 1024 blocks
    int cg = (bx >> 2) & 1;
    int b  = bx & 3;
    int qg = bx >> 3;                      // 0..127
    int q0 = qg * 32;
    int cb = cg * 128;

    int tid = threadIdx.x;
    int wv  = tid >> 6, lane = tid & 63;
    int m16 = lane & 15, qd = lane >> 4;
    int sw7 = m16 & 7, sw3 = m16 & 3;

    char* smem = (char*)Smem;
    unsigned short* Ps = (unsigned short*)(smem + 40960);
    float*          Lsh = (float*)(smem + 45056);

    // ---- DMA source offsets (swizzle folded into global src; LDS linear) ----
    int kgo, kl = wv * 1024;
    { int i = wv * 64 + lane; int row = i >> 2, pos = i & 3;
      kgo = (row * 4 + (pos ^ (row & 3))) * 16; }
    int vgo[4], vl[4];
    #pragma unroll
    for (int u = 0; u < 4; ++u) {
        int i = (wv * 4 + u) * 64 + lane; int row = i >> 3, pos = i & 7;
        vgo[u] = (row * 8 + (pos ^ (row & 7))) * 16;
        vl[u]  = (wv * 4 + u) * 1024;
    }

    const char* kbase = (const char*)k_t + (size_t)b * 262144;
    const char* vbase = (const char*)v_ws + (size_t)b * 2097152 + (size_t)cb * 128;

    // ---- persistent Q fragments (2 q-tiles) ----
    const unsigned short* qb = q_t + ((size_t)b * 4096 + q0) * 32;
    short8 Qf[2];
    #pragma unroll
    for (int qt = 0; qt < 2; ++qt)
        Qf[qt] = *(const short8*)(qb + (size_t)(qt * 16 + m16) * 32 + qd * 8);

    // ---- LDS read/write offsets ----
    int kro = (wv * 16 + m16) * 64 + ((qd ^ sw3) << 4);          // K frag, bytes
    int widx[2];
    #pragma unroll
    for (int qt = 0; qt < 2; ++qt)                                // P write, shorts
        widx[qt] = (qt * 16 + m16) * 64 + (((wv * 2 + (qd >> 1)) ^ sw7) << 3) + ((qd & 1) << 2);
    int apo[2][2];
    #pragma unroll
    for (int qt = 0; qt < 2; ++qt)                                // Ap read, shorts
        #pragma unroll
        for (int kc = 0; kc < 2; ++kc)
            apo[qt][kc] = (qt * 16 + m16) * 64 + (((kc * 4 + qd) ^ sw7) << 3);
    int vro[2];
    #pragma unroll
    for (int kc = 0; kc < 2; ++kc)                                // V frag chunk, bytes
        vro[kc] = ((kc * 4 + qd) ^ sw7) << 4;

    f32x4 zero4 = {0.f, 0.f, 0.f, 0.f};
    f32x4 acc[2][2];
    #pragma unroll
    for (int qt = 0; qt < 2; ++qt)
        #pragma unroll
        for (int ct = 0; ct < 2; ++ct) acc[qt][ct] = zero4;
    float lsum[2] = {0.f, 0.f};

    // prologue: stage tile 0 into buf 0
    glds16(kbase + kgo, smem + kl);
    #pragma unroll
    for (int u = 0; u < 4; ++u) glds16(vbase + vgo[u], smem + 8192 + vl[u]);

    #pragma unroll 1
    for (int it = 0; it < 64; ++it) {
        int z = it & 1;
        char* Kb = smem + z * 4096;
        char* Vb = smem + 8192 + z * 16384;

        // B1: tile-it staging complete (DMA issued one full iteration ago)
        asm volatile("s_waitcnt vmcnt(0)\n\ts_barrier" ::: "memory");

        short8 Kf = *(const short8*)(Kb + kro);

        if (it < 63) {    // stage tile it+1 into buf z^1 (readers done pre-B1)
            const char* ks = kbase + (size_t)(it + 1) * 4096;
            const char* vs = vbase + (size_t)(it + 1) * 32768;
            char* kd = smem + (z ^ 1) * 4096;
            char* vd = smem + 8192 + (z ^ 1) * 16384;
            glds16(ks + kgo, kd + kl);
            #pragma unroll
            for (int u = 0; u < 4; ++u) glds16(vs + vgo[u], vd + vl[u]);
        }

        // V fragments early (valid since B1); reused across both q-tiles
        short8 Vf[2][2];
        #pragma unroll
        for (int ct = 0; ct < 2; ++ct)
            #pragma unroll
            for (int kc = 0; kc < 2; ++kc)
                Vf[ct][kc] = *(const short8*)(Vb + (wv * 32 + ct * 16 + m16) * 128 + vro[kc]);

        // ---- QK: S^T (16k x 16q) per q-tile; k = wv*16 + 4*qd + r ----
        #pragma unroll
        for (int qt = 0; qt < 2; ++qt) {
            f32x4 S = __builtin_amdgcn_mfma_f32_16x16x32_bf16(Kf, Qf[qt], zero4, 0, 0, 0);
            float a0 = __builtin_amdgcn_exp2f(S.x), a1 = __builtin_amdgcn_exp2f(S.y);
            float a2 = __builtin_amdgcn_exp2f(S.z), a3 = __builtin_amdgcn_exp2f(S.w);
            lsum[qt] += (a0 + a1) + (a2 + a3);
            uint2 w; w.x = pack2bf(a0, a1); w.y = pack2bf(a2, a3);
            *(uint2*)&Ps[widx[qt]] = w;
        }

        // B2: P complete across waves; DMA stays in flight (no vmcnt drain)
        asm volatile("s_waitcnt lgkmcnt(0)\n\ts_barrier" ::: "memory");

        __builtin_amdgcn_s_setprio(1);
        short8 Ap[2][2];
        #pragma unroll
        for (int qt = 0; qt < 2; ++qt)
            #pragma unroll
            for (int kc = 0; kc < 2; ++kc)
                Ap[qt][kc] = *(const short8*)&Ps[apo[qt][kc]];
        #pragma unroll
        for (int qt = 0; qt < 2; ++qt)
            #pragma unroll
            for (int ct = 0; ct < 2; ++ct) {
                acc[qt][ct] = __builtin_amdgcn_mfma_f32_16x16x32_bf16(Ap[qt][0], Vf[ct][0], acc[qt][ct], 0, 0, 0);
                acc[qt][ct] = __builtin_amdgcn_mfma_f32_16x16x32_bf16(Ap[qt][1], Vf[ct][1], acc[qt][ct], 0, 0, 0);
            }
        __builtin_amdgcn_s_setprio(0);
    }

    // ---- softmax denominators: qd-reduce in-wave, key-slice combine in LDS ----
    #pragma unroll
    for (int qt = 0; qt < 2; ++qt) {
        float l = lsum[qt];
        l += __shfl_xor(l, 16);
        l += __shfl_xor(l, 32);
        if (lane < 16) Lsh[wv * 32 + qt * 16 + lane] = l;
    }
    asm volatile("s_waitcnt lgkmcnt(0)\n\ts_barrier" ::: "memory");

    #pragma unroll
    for (int qt = 0; qt < 2; ++qt) {
        f32x4 s4 = *(const f32x4*)&Lsh[qt * 16 + qd * 4];
        s4 += *(const f32x4*)&Lsh[32 + qt * 16 + qd * 4];
        s4 += *(const f32x4*)&Lsh[64 + qt * 16 + qd * 4];
        s4 += *(const f32x4*)&Lsh[96 + qt * 16 + qd * 4];
        f32x4 inv4;
        inv4.x = __builtin_amdgcn_rcpf(s4.x);
        inv4.y = __builtin_amdgcn_rcpf(s4.y);
        inv4.z = __builtin_amdgcn_rcpf(s4.z);
        inv4.w = __builtin_amdgcn_rcpf(s4.w);
        #pragma unroll
        for (int ct = 0; ct < 2; ++ct) {
            // acc: col=m16=c-local, row=4*qd+r=q-local
            float* ob = out + ((size_t)(b * 256 + cb + wv * 32 + ct * 16 + m16)) * 4096
                            + q0 + qt * 16 + qd * 4;
            float4 o;
            o.x = acc[qt][ct].x * inv4.x;
            o.y = acc[qt][ct].y * inv4.y;
            o.z = acc[qt][ct].z * inv4.z;
            o.w = acc[qt][ct].w * inv4.w;
            *(float4*)ob = o;
        }
    }
}

// ---------------------------------------------------------------------------
// Workspace: wq 320x256 bf16 | scale/off 320 f32 | q_t,k_t [b][n][32] bf16 |
// v_ws tile-blocked [b*64+kt][256][64] bf16. Total ~10.7 MB.
// ---------------------------------------------------------------------------
extern "C" void kernel_launch(void* const* d_in, const int* in_sizes, int n_in,
                              void* d_out, int out_size, void* d_ws, size_t ws_size,
                              hipStream_t stream)
{
    const float* x1  = (const float*)d_in[0];
    const float* x2  = (const float*)d_in[1];
    const float* qw  = (const float*)d_in[2];
    const float* qb  = (const float*)d_in[3];
    const float* qg  = (const float*)d_in[4];
    const float* qbe = (const float*)d_in[5];
    const float* qm  = (const float*)d_in[6];
    const float* qv  = (const float*)d_in[7];
    const float* kw  = (const float*)d_in[8];
    const float* kb  = (const float*)d_in[9];
    const float* kg  = (const float*)d_in[10];
    const float* kbe = (const float*)d_in[11];
    const float* km  = (const float*)d_in[12];
    const float* kvv = (const float*)d_in[13];
    const float* vw  = (const float*)d_in[14];
    const float* vb  = (const float*)d_in[15];
    const float* vg  = (const float*)d_in[16];
    const float* vbe = (const float*)d_in[17];
    const float* vm  = (const float*)d_in[18];
    const float* vv  = (const float*)d_in[19];

    char* ws = (char*)d_ws;
    unsigned short* wq   = (unsigned short*)(ws + 0);
    float*          scale= (float*)(ws + 163840);
    float*          off  = (float*)(ws + 165120);
    unsigned short* q_t  = (unsigned short*)(ws + 166400);
    unsigned short* k_t  = (unsigned short*)(ws + 166400 + 1048576);
    unsigned short* v_ws = (unsigned short*)(ws + 166400 + 2097152);

    prep_kernel<<<320, 64, 0, stream>>>(qw, qb, qg, qbe, qm, qv,
                                        kw, kb, kg, kbe, km, kvv,
                                        vw, vb, vg, vbe, vm, vv,
                                        wq, scale, off);
    proj_kernel<<<768, 256, 0, stream>>>(x1, x2, wq, scale, off, q_t, k_t, v_ws);
    flash_kernel<<<1024, 256, 0, stream>>>(q_t, k_t, v_ws, (float*)d_out);
}

// Round 8
// 173.162 us; speedup vs baseline: 1.5631x; 1.2647x over previous
//
#include <hip/hip_runtime.h>

using short8   = __attribute__((ext_vector_type(8))) short;
using f32x4    = __attribute__((ext_vector_type(4))) float;
using ushort4v = __attribute__((ext_vector_type(4))) unsigned short;

#define BN_EPS 1e-5f
// log2(e)/sqrt(32): folded into q projection so softmax uses native exp2
#define ATT_SCALE_LOG2E 0.2550348347988049f

__device__ __forceinline__ unsigned short f2bf(float f) {
    union { float f; unsigned u; } v; v.f = f;
    return (unsigned short)((v.u + 0x7FFFu + ((v.u >> 16) & 1u)) >> 16);  // RNE
}

// pack two f32 -> two bf16 (round-half-up): a in low 16, b in high 16
__device__ __forceinline__ unsigned pack2bf(float a, float b) {
    union { float f; unsigned u; } ua, ub; ua.f = a; ub.f = b;
    return __builtin_amdgcn_perm(ub.u + 0x8000u, ua.u + 0x8000u, 0x07060302u);
}

// async global->LDS, 16B per lane. gp: per-lane global src. lp: wave-uniform
// LDS base (HW adds lane*16).
__device__ __forceinline__ void glds16(const void* gp, void* lp) {
    __builtin_amdgcn_global_load_lds(
        (const __attribute__((address_space(1))) unsigned*)gp,
        (__attribute__((address_space(3))) unsigned*)lp, 16, 0, 0);
}

// ---------------------------------------------------------------------------
// Kernel 0: weights -> bf16; fold conv-bias + BN into per-row (scale, offset).
// Rows: 0-31 q, 32-63 k, 64-319 v.
// ---------------------------------------------------------------------------
__global__ void prep_kernel(
    const float* __restrict__ qw, const float* __restrict__ qb,
    const float* __restrict__ qg, const float* __restrict__ qbe,
    const float* __restrict__ qm, const float* __restrict__ qv,
    const float* __restrict__ kw, const float* __restrict__ kb,
    const float* __restrict__ kg, const float* __restrict__ kbe,
    const float* __restrict__ km, const float* __restrict__ kvv,
    const float* __restrict__ vw, const float* __restrict__ vb,
    const float* __restrict__ vg, const float* __restrict__ vbe,
    const float* __restrict__ vm, const float* __restrict__ vv,
    unsigned short* __restrict__ wq, float* __restrict__ scale,
    float* __restrict__ off)
{
    int r = blockIdx.x;      // 0..319
    int t = threadIdx.x;     // 0..63
    const float *wsrc, *g, *be, *mn, *vr, *bi;
    int rl;
    if (r < 32)      { rl = r;      wsrc = qw; g = qg; be = qbe; mn = qm; vr = qv;  bi = qb; }
    else if (r < 64) { rl = r - 32; wsrc = kw; g = kg; be = kbe; mn = km; vr = kvv; bi = kb; }
    else             { rl = r - 64; wsrc = vw; g = vg; be = vbe; mn = vm; vr = vv;  bi = vb; }

    float4 w4 = *(const float4*)(wsrc + rl * 256 + t * 4);
    ushort4v o;
    o.x = f2bf(w4.x); o.y = f2bf(w4.y); o.z = f2bf(w4.z); o.w = f2bf(w4.w);
    *(ushort4v*)(wq + r * 256 + t * 4) = o;

    if (t == 0) {
        float inv = g[rl] * rsqrtf(vr[rl] + BN_EPS);
        float ofv = bi[rl] * inv + be[rl] - mn[rl] * inv;
        float s = (r < 32) ? ATT_SCALE_LOG2E : 1.0f;
        scale[r] = inv * s;
        off[r]   = ofv * s;
    }
}

// ---------------------------------------------------------------------------
// Kernel 1: projections (r2 structure). bx>>8 = g: 0: q(x1), 1: k(x2),
// 2: v ALL 256 rows (x2). Grid 768. q_t/k_t: [b][n][32] bf16.
// v_ws: PAIR-INTERLEAVED tile-blocked layout for flash's fused-PV b128 reads:
//   [b][tp=0..31][c=0..255][16 granules x 16B], granule g (keys 4g..4g+3 of
//   the 64-key tile) = [tileA=2tp 8B | tileB=2tp+1 8B], granule slot
//   XOR-swizzled ONCE here: slot = (g&8) | ((g&7) ^ (c&7)). Flash DMAs this
//   image VERBATIM into linear LDS and applies the same swizzle on READ.
// ---------------------------------------------------------------------------
#define XT_PITCH 264

__global__ __launch_bounds__(256, 4) void proj_kernel(
    const float* __restrict__ x1, const float* __restrict__ x2,
    const unsigned short* __restrict__ wq,
    const float* __restrict__ scale, const float* __restrict__ off,
    unsigned short* __restrict__ q_t, unsigned short* __restrict__ k_t,
    unsigned short* __restrict__ v_ws)
{
    __shared__ __align__(16) unsigned short Xt[64 * XT_PITCH];   // 33792 B
    int bx = blockIdx.x;
    int g  = bx >> 8;        // 0,1,2
    int t2 = bx & 255;
    int nt = t2 & 63;
    int b  = t2 >> 6;
    int n0 = nt * 64;
    int tid = threadIdx.x;
    int wv = tid >> 6, lane = tid & 63;
    int m16 = lane & 15, qd = lane >> 4;

    const float* xb = ((g == 0) ? x1 : x2) + (size_t)b * 256 * 4096 + n0 + lane;

    // octet-gather transpose: n = lane, channels 8*o..8*o+7, o = wv*8+i
    #pragma unroll 2
    for (int i = 0; i < 8; ++i) {
        int o = wv * 8 + i;                       // 0..31
        const float* src = xb + (size_t)(o * 8) * 4096;
        uint4 dw;
        dw.x = pack2bf(src[0],                src[(size_t)1 * 4096]);
        dw.y = pack2bf(src[(size_t)2 * 4096], src[(size_t)3 * 4096]);
        dw.z = pack2bf(src[(size_t)4 * 4096], src[(size_t)5 * 4096]);
        dw.w = pack2bf(src[(size_t)6 * 4096], src[(size_t)7 * 4096]);
        *(uint4*)&Xt[lane * XT_PITCH + o * 8] = dw;
    }
    __syncthreads();

    f32x4 zero4 = {0.f, 0.f, 0.f, 0.f};

    if (g < 2) {
        int rb = g * 32;
        f32x4 acc0 = zero4, acc1 = zero4;
        #pragma unroll 2
        for (int s = 0; s < 8; ++s) {
            short8 w0 = *(const short8*)(wq + (size_t)(rb +      m16) * 256 + s * 32 + qd * 8);
            short8 w1 = *(const short8*)(wq + (size_t)(rb + 16 + m16) * 256 + s * 32 + qd * 8);
            short8 xf = *(const short8*)&Xt[(16 * wv + m16) * XT_PITCH + s * 32 + qd * 8];
            acc0 = __builtin_amdgcn_mfma_f32_16x16x32_bf16(w0, xf, acc0, 0, 0, 0);
            acc1 = __builtin_amdgcn_mfma_f32_16x16x32_bf16(w1, xf, acc1, 0, 0, 0);
        }
        unsigned short* dst = (g == 0) ? q_t : k_t;
        int ncol = n0 + 16 * wv + m16;
        #pragma unroll
        for (int tm = 0; tm < 2; ++tm) {
            f32x4 acc = tm ? acc1 : acc0;
            int r0 = 16 * tm + 4 * qd;
            float4 sc = *(const float4*)(scale + rb + r0);
            float4 of = *(const float4*)(off   + rb + r0);
            ushort4v o;
            o.x = f2bf(acc.x * sc.x + of.x);
            o.y = f2bf(acc.y * sc.y + of.y);
            o.z = f2bf(acc.z * sc.z + of.z);
            o.w = f2bf(acc.w * sc.w + of.w);
            *(ushort4v*)(dst + ((size_t)b * 4096 + ncol) * 32 + r0) = o;
        }
    } else {
        // v: all 256 rows from one x2 transpose
        f32x4 acc[4][4];
        #pragma unroll
        for (int rr = 0; rr < 4; ++rr)
            #pragma unroll
            for (int tm = 0; tm < 4; ++tm) acc[rr][tm] = zero4;
        #pragma unroll 1
        for (int s = 0; s < 8; ++s) {
            short8 xf[4];
            #pragma unroll
            for (int tm = 0; tm < 4; ++tm)
                xf[tm] = *(const short8*)&Xt[(16 * tm + m16) * XT_PITCH + s * 32 + qd * 8];
            #pragma unroll
            for (int rr = 0; rr < 4; ++rr) {
                short8 wf = *(const short8*)(wq + (size_t)(64 + rr * 64 + 16 * wv + m16) * 256 + s * 32 + qd * 8);
                #pragma unroll
                for (int tm = 0; tm < 4; ++tm)
                    acc[rr][tm] = __builtin_amdgcn_mfma_f32_16x16x32_bf16(xf[tm], wf, acc[rr][tm], 0, 0, 0);
            }
        }
        // pair-interleaved swizzled store
        unsigned short* vt = v_ws + ((size_t)b * 32 + (nt >> 1)) * 32768;
        int h = nt & 1;
        #pragma unroll
        for (int rr = 0; rr < 4; ++rr) {
            int c = rr * 64 + 16 * wv + m16;
            float sc = scale[64 + c], of = off[64 + c];
            #pragma unroll
            for (int tm = 0; tm < 4; ++tm) {
                int gg = 4 * tm + qd;                           // granule 0..15
                int gs = (gg & 8) | ((gg & 7) ^ (c & 7));       // swizzled slot
                ushort4v o;
                o.x = f2bf(acc[rr][tm].x * sc + of);
                o.y = f2bf(acc[rr][tm].y * sc + of);
                o.z = f2bf(acc[rr][tm].z * sc + of);
                o.w = f2bf(acc[rr][tm].w * sc + of);
                *(ushort4v*)(vt + c * 128 + gs * 8 + h * 4) = o;
            }
        }
    }
}

// ---------------------------------------------------------------------------
// Kernel 2: flash attention v7b — v2's DMA-staged V + v5's IN-REGISTER P.
// (v7 bug fixed: DMA source is now PLAIN LINEAR — the global image is already
// swizzled by proj, so the DMA copies it verbatim into linear LDS and only
// the ds_read applies the swizzle. v7 applied the involution twice on the
// write path, cancelling it.)
// Block = 4 waves (256 thr), 64q x 128c, grid 512 (2cg x 4b x 64qg, XCD-
// pinned via low 3 bits), 2 blocks/CU. Wave wv owns key-slice wv (16 keys
// per 64-key tile) through BOTH QK and PV: two tiles fused per PV MFMA
// (contraction slot s -> tile (s>>2)&1, key 4*(s>>3)+(s&3)), so the
// A-fragment is the wave's own exp2'd S values — P never touches LDS.
// Per 2-tile epoch: ONE barrier; DMA 32KB V-pair; PV B-frag = single
// swizzled ds_read_b128 (8-round minimum, conflict-free); K direct-global
// per-wave (1KB coalesced), prefetched a pair ahead. LDS traffic
// 64KB/pair/block vs v2's 160KB; barriers 32 vs 128. Per-wave acc =
// 64q x 128c (128 VGPR); end: 2-round conflict-free LDS tree.
// ---------------------------------------------------------------------------
__global__ __launch_bounds__(256, 2) void flash_kernel(
    const unsigned short* __restrict__ q_t, const unsigned short* __restrict__ k_t,
    const unsigned short* __restrict__ v_ws, float* __restrict__ out)
{
    __shared__ __align__(16) unsigned char Vb[2][32768];   // 64 KB V pair dbuf / scratch
    __shared__ __align__(16) float Lsh[256];               // 1 KB

    int bx = blockIdx.x;                   // 512 blocks
    int cg = (bx >> 2) & 1;
    int b  = bx & 3;
    int qg = bx >> 3;                      // 0..63
    int q0 = qg * 64;
    int cb = cg * 128;

    int tid = threadIdx.x;
    int wv  = tid >> 6, lane = tid & 63;   // wv = key-slice owner
    int m16 = lane & 15, qd = lane >> 4;

    // ---- V DMA: verbatim copy of the (pre-swizzled) global image ----
    // LDS linear addr i*16, i = (wv*8+u)*64 + lane -> plain [c_loc][slot]
    const char* vpb = (const char*)v_ws + (size_t)b * 2097152 + (size_t)cb * 256;
    int vgo[8], vl[8];
    #pragma unroll
    for (int u = 0; u < 8; ++u) {
        int i = (wv * 8 + u) * 64 + lane;          // 16B unit 0..2047
        vgo[u] = i * 16;                           // PLAIN linear source
        vl[u]  = (wv * 8 + u) * 1024;              // wave-uniform LDS base
    }
    // ---- V read offset: granule gw of row c_loc, swizzle applied on READ ----
    int gw = wv * 4 + qd;
    int gs = (gw & 8) | ((gw & 7) ^ (m16 & 7));
    int vro[8];
    #pragma unroll
    for (int ct = 0; ct < 8; ++ct) vro[ct] = (ct * 16 + m16) * 256 + gs * 16;

    // ---- K global base (wave's 16 rows, contiguous -> 1KB coalesced) ----
    const unsigned short* kbase = k_t + ((size_t)b * 4096 + wv * 16 + m16) * 32 + qd * 8;

    // ---- persistent Q fragments (all 4 q-tiles) ----
    const unsigned short* qb = q_t + ((size_t)b * 4096 + q0) * 32;
    short8 Qf[4];
    #pragma unroll
    for (int qt = 0; qt < 4; ++qt)
        Qf[qt] = *(const short8*)(qb + (size_t)(qt * 16 + m16) * 32 + qd * 8);

    f32x4 zero4 = {0.f, 0.f, 0.f, 0.f};
    f32x4 acc[4][8];
    #pragma unroll
    for (int qt = 0; qt < 4; ++qt)
        #pragma unroll
        for (int ct = 0; ct < 8; ++ct) acc[qt][ct] = zero4;
    float lsum[4] = {0.f, 0.f, 0.f, 0.f};

    // prologue: DMA V pair 0 into Vb[0]; K pair 0 into regs
    #pragma unroll
    for (int u = 0; u < 8; ++u) glds16(vpb + vgo[u], (char*)Vb + vl[u]);
    short8 KA0 = *(const short8*)kbase;
    short8 KA1 = *(const short8*)(kbase + 2048);
    short8 KB0 = KA0, KB1 = KA1;

    // one epoch: consume pair ep (K0c/K1c + Vcur); prefetch pair ep+1
    auto body = [&](const short8& K0c, const short8& K1c,
                    short8& K0n, short8& K1n,
                    char* Vcur, char* Vnxt, int ep) {
        // B1: pair-ep V staged + K regs arrived (issued a full epoch ago)
        asm volatile("s_waitcnt vmcnt(0)\n\ts_barrier" ::: "memory");

        if (ep < 31) {
            const char* vs = vpb + (size_t)(ep + 1) * 65536;
            #pragma unroll
            for (int u = 0; u < 8; ++u) glds16(vs + vgo[u], Vnxt + vl[u]);
            const unsigned short* ks = kbase + (size_t)(ep + 1) * 4096;
            K0n = *(const short8*)ks;
            K1n = *(const short8*)(ks + 2048);
        }

        // ---- QK both tiles: S^T 16k x 16q per qt; k-local = 4qd+r ----
        f32x4 SA[4], SB[4];
        #pragma unroll
        for (int qt = 0; qt < 4; ++qt) {
            SA[qt] = __builtin_amdgcn_mfma_f32_16x16x32_bf16(K0c, Qf[qt], zero4, 0, 0, 0);
            SB[qt] = __builtin_amdgcn_mfma_f32_16x16x32_bf16(K1c, Qf[qt], zero4, 0, 0, 0);
        }

        // ---- exp2 + in-lane fused A-frags (slots 0-3: tileA, 4-7: tileB) ----
        short8 ap[4];
        #pragma unroll
        for (int qt = 0; qt < 4; ++qt) {
            float a0 = __builtin_amdgcn_exp2f(SA[qt].x), a1 = __builtin_amdgcn_exp2f(SA[qt].y);
            float a2 = __builtin_amdgcn_exp2f(SA[qt].z), a3 = __builtin_amdgcn_exp2f(SA[qt].w);
            float b0 = __builtin_amdgcn_exp2f(SB[qt].x), b1 = __builtin_amdgcn_exp2f(SB[qt].y);
            float b2 = __builtin_amdgcn_exp2f(SB[qt].z), b3 = __builtin_amdgcn_exp2f(SB[qt].w);
            lsum[qt] += ((a0 + a1) + (a2 + a3)) + ((b0 + b1) + (b2 + b3));
            union { uint4 u; short8 s; } w;
            w.u.x = pack2bf(a0, a1); w.u.y = pack2bf(a2, a3);
            w.u.z = pack2bf(b0, b1); w.u.w = pack2bf(b2, b3);
            ap[qt] = w.s;
        }

        // ---- PV: 8 swizzled b128 B-frags, 32 MFMAs ----
        __builtin_amdgcn_s_setprio(1);
        #pragma unroll
        for (int ct = 0; ct < 8; ++ct) {
            short8 Vf = *(const short8*)(Vcur + vro[ct]);
            #pragma unroll
            for (int qt = 0; qt < 4; ++qt)
                acc[qt][ct] = __builtin_amdgcn_mfma_f32_16x16x32_bf16(ap[qt], Vf, acc[qt][ct], 0, 0, 0);
        }
        __builtin_amdgcn_s_setprio(0);
    };

    #pragma unroll 1
    for (int ep = 0; ep < 32; ep += 2) {
        body(KA0, KA1, KB0, KB1, (char*)Vb[0], (char*)Vb[1], ep);
        body(KB0, KB1, KA0, KA1, (char*)Vb[1], (char*)Vb[0], ep + 1);
    }

    // ---- denominators: reduce over qd in-wave; publish per key-slice ----
    #pragma unroll
    for (int qt = 0; qt < 4; ++qt) {
        float l = lsum[qt];
        l += __shfl_xor(l, 16);
        l += __shfl_xor(l, 32);
        if (lane < 16) Lsh[wv * 64 + qt * 16 + lane] = l;
    }

    // ---- O-combine over key-slices: 2-round conflict-free LDS tree ----
    char* X = (char*)Vb;   // 64 KB scratch (V bufs dead; DMA drained below)
    asm volatile("s_waitcnt vmcnt(0) lgkmcnt(0)\n\ts_barrier" ::: "memory");
    if (wv >= 2) {
        char* dst = X + (size_t)(wv - 2) * 32768;
        #pragma unroll
        for (int qt = 0; qt < 4; ++qt)
            #pragma unroll
            for (int ct = 0; ct < 8; ++ct)
                *(f32x4*)(dst + (qt * 8 + ct) * 1024 + lane * 16) = acc[qt][ct];
    }
    asm volatile("s_waitcnt lgkmcnt(0)\n\ts_barrier" ::: "memory");
    if (wv < 2) {
        const char* src = X + (size_t)wv * 32768;
        #pragma unroll
        for (int qt = 0; qt < 4; ++qt)
            #pragma unroll
            for (int ct = 0; ct < 8; ++ct)
                acc[qt][ct] += *(const f32x4*)(src + (qt * 8 + ct) * 1024 + lane * 16);
    }
    asm volatile("s_waitcnt lgkmcnt(0)\n\ts_barrier" ::: "memory");
    if (wv == 1) {
        char* dst = X + 32768;
        #pragma unroll
        for (int qt = 0; qt < 4; ++qt)
            #pragma unroll
            for (int ct = 0; ct < 8; ++ct)
                *(f32x4*)(dst + (qt * 8 + ct) * 1024 + lane * 16) = acc[qt][ct];
    }
    asm volatile("s_waitcnt lgkmcnt(0)\n\ts_barrier" ::: "memory");
    if (wv == 0) {
        const char* src = X + 32768;
        #pragma unroll
        for (int qt = 0; qt < 4; ++qt)
            #pragma unroll
            for (int ct = 0; ct < 8; ++ct)
                acc[qt][ct] += *(const f32x4*)(src + (qt * 8 + ct) * 1024 + lane * 16);

        #pragma unroll
        for (int qt = 0; qt < 4; ++qt) {
            f32x4 s4 = *(const f32x4*)&Lsh[qt * 16 + qd * 4];
            s4 += *(const f32x4*)&Lsh[64  + qt * 16 + qd * 4];
            s4 += *(const f32x4*)&Lsh[128 + qt * 16 + qd * 4];
            s4 += *(const f32x4*)&Lsh[192 + qt * 16 + qd * 4];
            f32x4 inv4;
            inv4.x = __builtin_amdgcn_rcpf(s4.x);
            inv4.y = __builtin_amdgcn_rcpf(s4.y);
            inv4.z = __builtin_amdgcn_rcpf(s4.z);
            inv4.w = __builtin_amdgcn_rcpf(s4.w);
            #pragma unroll
            for (int ct = 0; ct < 8; ++ct) {
                // acc: col=m16=c-local, row=4*qd+r=q-local
                float* ob = out + ((size_t)(b * 256 + cb + ct * 16 + m16)) * 4096
                                + q0 + qt * 16 + qd * 4;
                float4 o;
                o.x = acc[qt][ct].x * inv4.x;
                o.y = acc[qt][ct].y * inv4.y;
                o.z = acc[qt][ct].z * inv4.z;
                o.w = acc[qt][ct].w * inv4.w;
                *(float4*)ob = o;
            }
        }
    }
}

// ---------------------------------------------------------------------------
// Workspace: wq 320x256 bf16 | scale/off 320 f32 | q_t,k_t [b][n][32] bf16 |
// v_ws pair-interleaved [b][tp=32][256][16x16B]. Total ~10.7 MB.
// ---------------------------------------------------------------------------
extern "C" void kernel_launch(void* const* d_in, const int* in_sizes, int n_in,
                              void* d_out, int out_size, void* d_ws, size_t ws_size,
                              hipStream_t stream)
{
    const float* x1  = (const float*)d_in[0];
    const float* x2  = (const float*)d_in[1];
    const float* qw  = (const float*)d_in[2];
    const float* qb  = (const float*)d_in[3];
    const float* qg  = (const float*)d_in[4];
    const float* qbe = (const float*)d_in[5];
    const float* qm  = (const float*)d_in[6];
    const float* qv  = (const float*)d_in[7];
    const float* kw  = (const float*)d_in[8];
    const float* kb  = (const float*)d_in[9];
    const float* kg  = (const float*)d_in[10];
    const float* kbe = (const float*)d_in[11];
    const float* km  = (const float*)d_in[12];
    const float* kvv = (const float*)d_in[13];
    const float* vw  = (const float*)d_in[14];
    const float* vb  = (const float*)d_in[15];
    const float* vg  = (const float*)d_in[16];
    const float* vbe = (const float*)d_in[17];
    const float* vm  = (const float*)d_in[18];
    const float* vv  = (const float*)d_in[19];

    char* ws = (char*)d_ws;
    unsigned short* wq   = (unsigned short*)(ws + 0);
    float*          scale= (float*)(ws + 163840);
    float*          off  = (float*)(ws + 165120);
    unsigned short* q_t  = (unsigned short*)(ws + 166400);
    unsigned short* k_t  = (unsigned short*)(ws + 166400 + 1048576);
    unsigned short* v_ws = (unsigned short*)(ws + 166400 + 2097152);

    prep_kernel<<<320, 64, 0, stream>>>(qw, qb, qg, qbe, qm, qv,
                                        kw, kb, kg, kbe, km, kvv,
                                        vw, vb, vg, vbe, vm, vv,
                                        wq, scale, off);
    proj_kernel<<<768, 256, 0, stream>>>(x1, x2, wq, scale, off, q_t, k_t, v_ws);
    flash_kernel<<<512, 256, 0, stream>>>(q_t, k_t, v_ws, (float*)d_out);
}